// Round 6
// baseline (203.045 us; speedup 1.0000x reference)
//
#include <hip/hip_runtime.h>

// B=8, L=512, K=512, D=M=N=P=64, all fp32.
// ws: vkc = 8*512*64 floats (1 MB) | wts = 8*512*512 floats (8 MB)

// ---------------------------------------------------------------------------
// K_A: per block (256 thr): 4 vkc rows (streamed) THEN scores+softmax for
// 4 l-rows -> weights to global. vk stream overlaps scores compute across
// drifting waves/blocks (one barrier total before the scores phase).
// ---------------------------------------------------------------------------
__global__ __launch_bounds__(256) void pre_kernel(const float* __restrict__ q,
                                                  const float* __restrict__ k,
                                                  const float* __restrict__ vk,
                                                  const float* __restrict__ vexp,
                                                  const float* __restrict__ scale_p,
                                                  float* __restrict__ vkc,
                                                  float* __restrict__ wts) {
    __shared__ float q_s[4 * 64];         // 1 KB
    __shared__ float sc[4][512];          // 8 KB

    const int t = threadIdx.x;
    const int wv = t >> 6;                // 0..3
    const int lane = t & 63;
    const int batch = blockIdx.x >> 7;    // same batch for vkc rows and scores
    const int l0 = (blockIdx.x & 127) << 2;

    const float scale = scale_p[0];

    // stage q rows first (one coalesced instr; consumed after the barrier)
    q_s[t] = q[(batch * 512 + l0) * 64 + t];

    // ---- vkc: wave wv handles row = bid*4+wv (proven R1 pattern) ----
    {
        const int row = (blockIdx.x << 2) + wv;       // b*512 + kk
        const float ve = vexp[row * 64 + lane];
        const int n0 = (lane & 15) << 2;
        const float* base = vk + (long)row * 4096;
        float ax = 0.f, ay = 0.f, az = 0.f, aw = 0.f;
        #pragma unroll
        for (int it = 0; it < 16; ++it) {
            const int p = (lane >> 4) + (it << 2);
            const float4 v4 = *(const float4*)(base + p * 64 + n0);
            const float w = __shfl(ve, p, 64);
            ax += v4.x * w; ay += v4.y * w; az += v4.z * w; aw += v4.w * w;
        }
        ax += __shfl_down(ax, 32, 64); ax += __shfl_down(ax, 16, 64);
        ay += __shfl_down(ay, 32, 64); ay += __shfl_down(ay, 16, 64);
        az += __shfl_down(az, 32, 64); az += __shfl_down(az, 16, 64);
        aw += __shfl_down(aw, 32, 64); aw += __shfl_down(aw, 16, 64);
        if ((lane & 48) == 0) {
            float4 r; r.x = ax; r.y = ay; r.z = az; r.w = aw;
            *(float4*)(vkc + row * 64 + n0) = r;
        }
    }
    __syncthreads();   // q_s ready (and waves roughly re-converge)

    // ---- scores: thread t owns k-rows t and t+256; 4 l-dots each ----
    {
        const float* kb = k + batch * 512 * 64;
        const float4* q4 = (const float4*)q_s;
        #pragma unroll
        for (int rep = 0; rep < 2; ++rep) {
            const int kk = t + (rep << 8);
            const float4* krow = (const float4*)(kb + kk * 64);
            float a0 = 0.f, a1 = 0.f, a2 = 0.f, a3 = 0.f;
            #pragma unroll
            for (int dc = 0; dc < 16; ++dc) {
                const float4 kv = krow[dc];                 // 1 KB/wave-instr
                const float4 p0 = q4[dc];                   // LDS broadcast
                const float4 p1 = q4[16 + dc];
                const float4 p2 = q4[32 + dc];
                const float4 p3 = q4[48 + dc];
                a0 += p0.x * kv.x + p0.y * kv.y + p0.z * kv.z + p0.w * kv.w;
                a1 += p1.x * kv.x + p1.y * kv.y + p1.z * kv.z + p1.w * kv.w;
                a2 += p2.x * kv.x + p2.y * kv.y + p2.z * kv.z + p2.w * kv.w;
                a3 += p3.x * kv.x + p3.y * kv.y + p3.z * kv.z + p3.w * kv.w;
            }
            sc[0][kk] = scale * a0;
            sc[1][kk] = scale * a1;
            sc[2][kk] = scale * a2;
            sc[3][kk] = scale * a3;
        }
    }
    __syncthreads();

    // ---- softmax over K=512; wave wv -> l=wv; weights straight to global ----
    {
        float v[8]; float mx = -1e30f;
        #pragma unroll
        for (int j = 0; j < 8; ++j) { v[j] = sc[wv][lane + 64 * j]; mx = fmaxf(mx, v[j]); }
        #pragma unroll
        for (int off = 32; off; off >>= 1) mx = fmaxf(mx, __shfl_xor(mx, off, 64));
        float s = 0.f;
        #pragma unroll
        for (int j = 0; j < 8; ++j) { v[j] = __expf(v[j] - mx); s += v[j]; }
        #pragma unroll
        for (int off = 32; off; off >>= 1) s += __shfl_xor(s, off, 64);
        const float inv = 1.0f / s;
        float* wrow = wts + (long)(batch * 512 + l0 + wv) * 512;
        #pragma unroll
        for (int j = 0; j < 8; ++j) wrow[lane + 64 * j] = v[j] * inv;  // coalesced
    }
}

// ---------------------------------------------------------------------------
// K_B: per block (256 thr): stage 4 weight rows -> tmp = w @ vkc (float4,
// 16 chains/wave) -> attn = vq.tmp -> residual + LN. 4 blocks/CU keeps the
// vq stream of some blocks overlapped with tmp compute of others.
// ---------------------------------------------------------------------------
__global__ __launch_bounds__(256) void post_kernel(const float* __restrict__ q,
                                                   const float* __restrict__ vq,
                                                   const float* __restrict__ vkc,
                                                   const float* __restrict__ wts,
                                                   const float* __restrict__ gamma,
                                                   const float* __restrict__ beta,
                                                   float* __restrict__ out) {
    __shared__ float w_s[4 * 512];        // 8 KB
    __shared__ float tp[4][4][64];        // 4 KB
    __shared__ float tmp_s[4 * 64];       // 1 KB
    __shared__ float attn_s[4][64];       // 1 KB

    const int t = threadIdx.x;
    const int wv = t >> 6;
    const int lane = t & 63;
    const int batch = blockIdx.x >> 7;
    const int l0 = (blockIdx.x & 127) << 2;

    // ---- stage 4 weight rows (2 KB each; coalesced float4) ----
    {
        const float* wg = wts + (long)(batch * 512 + l0) * 512;
        #pragma unroll
        for (int i = 0; i < 2; ++i)
            *(float4*)(w_s + t * 4 + i * 1024) = *(const float4*)(wg + t * 4 + i * 1024);
    }
    __syncthreads();

    // ---- tmp[l][n] = sum_k w[l][k]*vkc[b][k][n]; wave covers 128 k ----
    {
        const float* vkcb = vkc + batch * 512 * 64;
        const int ksub = lane >> 4;
        const int n0 = (lane & 15) << 2;
        const int kbeg = wv << 7;
        float4 a[4];
        #pragma unroll
        for (int l = 0; l < 4; ++l) { a[l].x = 0.f; a[l].y = 0.f; a[l].z = 0.f; a[l].w = 0.f; }
        #pragma unroll 8
        for (int i = 0; i < 32; ++i) {
            const int kk = kbeg + (i << 2) + ksub;
            const float4 v4 = *(const float4*)(vkcb + kk * 64 + n0);  // 1 KB, L2-hot
            #pragma unroll
            for (int l = 0; l < 4; ++l) {
                const float w = w_s[l * 512 + kk];
                a[l].x += w * v4.x; a[l].y += w * v4.y;
                a[l].z += w * v4.z; a[l].w += w * v4.w;
            }
        }
        #pragma unroll
        for (int l = 0; l < 4; ++l) {
            a[l].x += __shfl_down(a[l].x, 32, 64); a[l].x += __shfl_down(a[l].x, 16, 64);
            a[l].y += __shfl_down(a[l].y, 32, 64); a[l].y += __shfl_down(a[l].y, 16, 64);
            a[l].z += __shfl_down(a[l].z, 32, 64); a[l].z += __shfl_down(a[l].z, 16, 64);
            a[l].w += __shfl_down(a[l].w, 32, 64); a[l].w += __shfl_down(a[l].w, 16, 64);
        }
        if (lane < 16) {
            #pragma unroll
            for (int l = 0; l < 4; ++l)
                *(float4*)&tp[wv][l][lane << 2] = a[l];
        }
    }
    __syncthreads();
    {   // reduce the 4 wave partials; t = l*64 + n
        const int l = t >> 6, n = t & 63;
        tmp_s[t] = tp[0][l][n] + tp[1][l][n] + tp[2][l][n] + tp[3][l][n];
    }
    __syncthreads();

    // ---- attn[l][m] = sum_n vq[b,l,m,n]*tmp[l][n]; wave wv -> l=wv ----
    {
        const float* vql = vq + (long)(batch * 512 + l0 + wv) * 4096;
        const int n0 = (lane & 15) << 2;
        const float4 t4 = *(const float4*)&tmp_s[wv * 64 + n0];
        #pragma unroll
        for (int it = 0; it < 16; ++it) {
            const float4 v4 = *(const float4*)(vql + it * 256 + lane * 4); // 1 KB
            float part = v4.x * t4.x + v4.y * t4.y + v4.z * t4.z + v4.w * t4.w;
            part += __shfl_down(part, 8, 16);
            part += __shfl_down(part, 4, 16);
            part += __shfl_down(part, 2, 16);
            part += __shfl_down(part, 1, 16);
            if ((lane & 15) == 0) attn_s[wv][it * 4 + (lane >> 4)] = part;
        }
    }
    // attn_s[wv] produced+consumed by the same wave -> no barrier

    // ---- residual + LayerNorm over D=64; wave wv -> l=wv ----
    {
        const int row = batch * 512 + l0 + wv;
        const float x = q[row * 64 + lane] + attn_s[wv][lane];
        float s1 = x, s2 = x * x;
        #pragma unroll
        for (int off = 32; off; off >>= 1) {
            s1 += __shfl_xor(s1, off, 64);
            s2 += __shfl_xor(s2, off, 64);
        }
        const float mean = s1 * (1.0f / 64.0f);
        const float var = s2 * (1.0f / 64.0f) - mean * mean;
        const float r = rsqrtf(var + 1e-3f);
        out[row * 64 + lane] = (x - mean) * r * gamma[lane] + beta[lane];
    }
}

extern "C" void kernel_launch(void* const* d_in, const int* in_sizes, int n_in,
                              void* d_out, int out_size, void* d_ws, size_t ws_size,
                              hipStream_t stream) {
    const float* q     = (const float*)d_in[0];
    const float* k     = (const float*)d_in[1];
    const float* vq    = (const float*)d_in[2];
    const float* vk    = (const float*)d_in[3];
    const float* vexp  = (const float*)d_in[4];
    const float* scale = (const float*)d_in[5];
    const float* gamma = (const float*)d_in[6];
    const float* beta  = (const float*)d_in[7];
    float* out = (float*)d_out;

    float* vkc = (float*)d_ws;                 // 1 MB
    float* wts = vkc + 8 * 512 * 64;           // 8 MB

    pre_kernel<<<1024, 256, 0, stream>>>(q, k, vk, vexp, scale, vkc, wts);
    post_kernel<<<1024, 256, 0, stream>>>(q, vq, vkc, wts, gamma, beta, out);
}

// Round 7
// 179.964 us; speedup vs baseline: 1.1283x; 1.1283x over previous
//
#include <hip/hip_runtime.h>

// B=8, L=512, K=512, D=M=N=P=64, all fp32.
// ws: vkc = 8*512*64 floats (1 MB) | tmp = 8*512*64 floats (1 MB)

// ---------------------------------------------------------------------------
// K1 (proven, ~6.2 TB/s): vkc[b,k,n] = sum_p vk[b,k,p,n] * vexp[b,k,p]
// ---------------------------------------------------------------------------
__global__ __launch_bounds__(256) void vkc_kernel(const float* __restrict__ vk,
                                                  const float* __restrict__ vexp,
                                                  float* __restrict__ vkc) {
    const int wave = (blockIdx.x << 2) + (threadIdx.x >> 6);  // b*512 + k
    const int lane = threadIdx.x & 63;

    const float ve_reg = vexp[wave * 64 + lane];
    const int n0 = (lane & 15) << 2;
    const float* base = vk + (long)wave * 4096;

    float ax = 0.f, ay = 0.f, az = 0.f, aw = 0.f;
    #pragma unroll
    for (int it = 0; it < 16; ++it) {
        const int p = (lane >> 4) + (it << 2);
        const float4 v4 = *(const float4*)(base + p * 64 + n0);
        const float w = __shfl(ve_reg, p, 64);
        ax += v4.x * w; ay += v4.y * w; az += v4.z * w; aw += v4.w * w;
    }
    ax += __shfl_down(ax, 32, 64); ax += __shfl_down(ax, 16, 64);
    ay += __shfl_down(ay, 32, 64); ay += __shfl_down(ay, 16, 64);
    az += __shfl_down(az, 32, 64); az += __shfl_down(az, 16, 64);
    aw += __shfl_down(aw, 32, 64); aw += __shfl_down(aw, 16, 64);

    if ((lane & 48) == 0) {
        float4 r; r.x = ax; r.y = ay; r.z = az; r.w = aw;
        *(float4*)(vkc + wave * 64 + n0) = r;
    }
}

// ---------------------------------------------------------------------------
// K2: per (batch, 8 l-rows), 512 threads: scores -> softmax -> tmp (global).
// q is read via block-uniform global indices -> scalar loads (s_load_dwordx4,
// constant cache) -- NO LDS traffic in phase 1 (was 128 ds_read_b128/wave).
// ---------------------------------------------------------------------------
__global__ __launch_bounds__(512) void score_tmp_kernel(const float* __restrict__ q,
                                                        const float* __restrict__ k,
                                                        const float* __restrict__ vkc,
                                                        const float* __restrict__ scale_p,
                                                        float* __restrict__ tmp_g) {
    __shared__ float sc[8][512];          // 16 KB
    __shared__ float tp[8][8][64];        // 16 KB

    const int t = threadIdx.x;
    const int wv = t >> 6;
    const int lane = t & 63;
    const int batch = blockIdx.x >> 6;
    const int l0 = (blockIdx.x & 63) << 3;

    const float scale = scale_p[0];
    const float* qbase = q + (batch * 512 + l0) * 64;   // block-uniform

    // ---- phase 1: thread t owns k-row t; 8 l-dots; q on the scalar pipe ----
    {
        const float4* krow = (const float4*)(k + (batch * 512 + t) * 64);
        float acc[8] = {0.f, 0.f, 0.f, 0.f, 0.f, 0.f, 0.f, 0.f};
        #pragma unroll
        for (int dc = 0; dc < 16; ++dc) {
            const float4 kv = krow[dc];                  // 1 KB/wave-instr
            #pragma unroll
            for (int l = 0; l < 8; ++l) {
                const float4 qv = ((const float4*)(qbase + l * 64))[dc]; // uniform -> s_load
                acc[l] += qv.x * kv.x + qv.y * kv.y + qv.z * kv.z + qv.w * kv.w;
            }
        }
        #pragma unroll
        for (int l = 0; l < 8; ++l) sc[l][t] = scale * acc[l];  // coalesced LDS
    }
    __syncthreads();

    // ---- phase 2: softmax over K=512; wave wv -> l=wv ----
    {
        float v[8]; float mx = -1e30f;
        #pragma unroll
        for (int j = 0; j < 8; ++j) { v[j] = sc[wv][lane + 64 * j]; mx = fmaxf(mx, v[j]); }
        #pragma unroll
        for (int off = 32; off; off >>= 1) mx = fmaxf(mx, __shfl_xor(mx, off, 64));
        float s = 0.f;
        #pragma unroll
        for (int j = 0; j < 8; ++j) { v[j] = __expf(v[j] - mx); s += v[j]; }
        #pragma unroll
        for (int off = 32; off; off >>= 1) s += __shfl_xor(s, off, 64);
        const float inv = 1.0f / s;
        #pragma unroll
        for (int j = 0; j < 8; ++j) sc[wv][lane + 64 * j] = v[j] * inv;
    }
    __syncthreads();

    // ---- phase 3: tmp[l][n] = sum_k w[l][k]*vkc[b][k][n]; wave covers 64 k --
    {
        const float* vkcb = vkc + batch * 512 * 64;
        const int ksub = lane >> 4;
        const int n0 = (lane & 15) << 2;
        const int kbeg = wv << 6;
        float4 a[8];
        #pragma unroll
        for (int l = 0; l < 8; ++l) { a[l].x = 0.f; a[l].y = 0.f; a[l].z = 0.f; a[l].w = 0.f; }
        #pragma unroll
        for (int i = 0; i < 16; ++i) {
            const int kk = kbeg + (i << 2) + ksub;
            const float4 v4 = *(const float4*)(vkcb + kk * 64 + n0);  // 1 KB/instr
            #pragma unroll
            for (int l = 0; l < 8; ++l) {
                const float w = sc[l][kk];
                a[l].x += w * v4.x; a[l].y += w * v4.y;
                a[l].z += w * v4.z; a[l].w += w * v4.w;
            }
        }
        #pragma unroll
        for (int l = 0; l < 8; ++l) {
            a[l].x += __shfl_down(a[l].x, 32, 64); a[l].x += __shfl_down(a[l].x, 16, 64);
            a[l].y += __shfl_down(a[l].y, 32, 64); a[l].y += __shfl_down(a[l].y, 16, 64);
            a[l].z += __shfl_down(a[l].z, 32, 64); a[l].z += __shfl_down(a[l].z, 16, 64);
            a[l].w += __shfl_down(a[l].w, 32, 64); a[l].w += __shfl_down(a[l].w, 16, 64);
        }
        if (lane < 16) {
            #pragma unroll
            for (int l = 0; l < 8; ++l)
                *(float4*)&tp[wv][l][lane << 2] = a[l];
        }
    }
    __syncthreads();
    {   // reduce the 8 wave partials and write tmp to global (coalesced)
        float s = tp[0][wv][lane];
        #pragma unroll
        for (int w = 1; w < 8; ++w) s += tp[w][wv][lane];
        tmp_g[(batch * 512 + l0) * 64 + t] = s;
    }
}

// ---------------------------------------------------------------------------
// K3 (proven): one wave per (b,l) row: attn = vq.tmp -> residual + LN.
// Zero block barriers; 16 hoisted 1 KB coalesced loads per wave.
// ---------------------------------------------------------------------------
__global__ __launch_bounds__(256) void out_kernel(const float* __restrict__ q,
                                                  const float* __restrict__ vq,
                                                  const float* __restrict__ tmp_g,
                                                  const float* __restrict__ gamma,
                                                  const float* __restrict__ beta,
                                                  float* __restrict__ out) {
    __shared__ float attn_s[4][64];

    const int wv = threadIdx.x >> 6;
    const int lane = threadIdx.x & 63;
    const int row = (blockIdx.x << 2) + wv;        // b*512 + l

    const float* vql = vq + (long)row * 4096;

    float4 v[16];
    #pragma unroll
    for (int it = 0; it < 16; ++it)
        v[it] = *(const float4*)(vql + it * 256 + lane * 4);

    const float qv = q[row * 64 + lane];
    const int n0 = (lane & 15) << 2;
    const float4 t4 = *(const float4*)(tmp_g + row * 64 + n0);

    #pragma unroll
    for (int it = 0; it < 16; ++it) {
        float part = v[it].x * t4.x + v[it].y * t4.y + v[it].z * t4.z + v[it].w * t4.w;
        part += __shfl_down(part, 8, 16);
        part += __shfl_down(part, 4, 16);
        part += __shfl_down(part, 2, 16);
        part += __shfl_down(part, 1, 16);
        if ((lane & 15) == 0) attn_s[wv][it * 4 + (lane >> 4)] = part;
    }
    // attn_s[wv] produced+consumed by the same wave -> no block barrier

    const float x = qv + attn_s[wv][lane];
    float s1 = x, s2 = x * x;
    #pragma unroll
    for (int off = 32; off; off >>= 1) {
        s1 += __shfl_xor(s1, off, 64);
        s2 += __shfl_xor(s2, off, 64);
    }
    const float mean = s1 * (1.0f / 64.0f);
    const float var = s2 * (1.0f / 64.0f) - mean * mean;
    const float r = rsqrtf(var + 1e-3f);
    out[row * 64 + lane] = (x - mean) * r * gamma[lane] + beta[lane];
}

extern "C" void kernel_launch(void* const* d_in, const int* in_sizes, int n_in,
                              void* d_out, int out_size, void* d_ws, size_t ws_size,
                              hipStream_t stream) {
    const float* q     = (const float*)d_in[0];
    const float* k     = (const float*)d_in[1];
    const float* vq    = (const float*)d_in[2];
    const float* vk    = (const float*)d_in[3];
    const float* vexp  = (const float*)d_in[4];
    const float* scale = (const float*)d_in[5];
    const float* gamma = (const float*)d_in[6];
    const float* beta  = (const float*)d_in[7];
    float* out = (float*)d_out;

    float* vkc = (float*)d_ws;                 // 1 MB
    float* tmp = vkc + 8 * 512 * 64;           // 1 MB

    vkc_kernel<<<1024, 256, 0, stream>>>(vk, vexp, vkc);
    score_tmp_kernel<<<512, 512, 0, stream>>>(q, k, vkc, scale, tmp);
    out_kernel<<<1024, 256, 0, stream>>>(q, vq, tmp, gamma, beta, out);
}